// Round 10
// baseline (238.461 us; speedup 1.0000x reference)
//
#include <hip/hip_runtime.h>
#include <math.h>

#define TOK 32768
#define CH  256
#define HIDN 1024
#define NE  8
#define BE  10240
#define CNT_STRIDE 64

typedef __attribute__((ext_vector_type(8))) short bf16x8;
typedef __attribute__((ext_vector_type(4))) float f32x4;

__device__ __forceinline__ unsigned short f2bf(float f) {
    unsigned u = __builtin_bit_cast(unsigned, f);
    unsigned r = 0x7FFFu + ((u >> 16) & 1u);
    return (unsigned short)((u + r) >> 16);
}
__device__ __forceinline__ float bf2f(unsigned short u) {
    return __builtin_bit_cast(float, (unsigned)u << 16);
}
__device__ __forceinline__ unsigned pk8_lo(float a, float b, unsigned old) {
    return (unsigned)__builtin_amdgcn_cvt_pk_fp8_f32(a, b, (int)old, false);
}
__device__ __forceinline__ unsigned pk8_hi(float a, float b, unsigned old) {
    return (unsigned)__builtin_amdgcn_cvt_pk_fp8_f32(a, b, (int)old, true);
}
__device__ __forceinline__ f32x4 mfma8(long a, long b, f32x4 c) {
    return __builtin_amdgcn_mfma_f32_16x16x32_fp8_fp8(a, b, c, 0, 0, 0);
}

typedef __attribute__((address_space(3))) void lds_t;
typedef const __attribute__((address_space(1))) void gm_t;
#define GL16(gp, lp) __builtin_amdgcn_global_load_lds((gm_t*)(gp), (lds_t*)(lp), 16, 0, 0)

__global__ void k_init(int* cnt) { cnt[threadIdx.x] = 0; }

// Depthwise 7x7 conv + bias. Block = one (n,c) image staged to LDS; each thread
// computes a 4-output vertical column. Output NCHW bf16, fully coalesced.
__global__ __launch_bounds__(256) void k_conv(const float* __restrict__ in,
                                              const float* __restrict__ kern,
                                              const float* __restrict__ bias,
                                              unsigned short* __restrict__ xcb) {
    __shared__ float img[1024];
    __shared__ float kwl[49];
    int t = threadIdx.x;
    int bid = blockIdx.x;          // bid = n*256 + c
    int c = bid & 255;

    GL16(in + (size_t)bid * 1024 + t * 4, (char*)img + t * 16);
    if (t < 49) kwl[t] = kern[c * 49 + t];
    __syncthreads();

    int x = t & 31, y0 = (t >> 5) * 4;
    float b0 = bias[c];
    float acc[4] = {b0, b0, b0, b0};
#pragma unroll
    for (int rr = 0; rr < 10; ++rr) {
        int r = y0 - 3 + rr;
        if ((unsigned)r < 32u) {
#pragma unroll
            for (int dx = -3; dx <= 3; ++dx) {
                int xx = x + dx;
                if ((unsigned)xx < 32u) {
                    float v = img[r * 32 + xx];
#pragma unroll
                    for (int o = 0; o < 4; ++o) {
                        int jr = rr - o;
                        if (0 <= jr && jr <= 6)
                            acc[o] = fmaf(v, kwl[jr * 7 + (dx + 3)], acc[o]);
                    }
                }
            }
        }
    }
#pragma unroll
    for (int o = 0; o < 4; ++o)
        xcb[(size_t)bid * 1024 + (y0 + o) * 32 + x] = f2bf(acc[o]);
}

// LN + router: block = (n,y) row. Coalesced bf16 loads, LDS transpose, wave LN.
__global__ __launch_bounds__(512) void k_lnr(const unsigned short* __restrict__ xcb,
                                             const float* __restrict__ gamma,
                                             const float* __restrict__ beta,
                                             const float* __restrict__ rw,
                                             unsigned* __restrict__ xf8,
                                             int* __restrict__ e01,
                                             float2* __restrict__ gates) {
    __shared__ float acc[32][260];
    int t = threadIdx.x;
    int n = blockIdx.x >> 5, y = blockIdx.x & 31;
    int x = t & 31, ch = t >> 5;

    float vals[16];
#pragma unroll
    for (int i = 0; i < 16; ++i) {
        int c = i * 16 + ch;
        vals[i] = bf2f(xcb[((size_t)(n * 256 + c)) * 1024 + y * 32 + x]);
    }
#pragma unroll
    for (int i = 0; i < 16; ++i) acc[x][i * 16 + ch] = vals[i];
    __syncthreads();

    int lane = t & 63, w = t >> 6;
    float4 g4 = ((const float4*)gamma)[lane];
    float4 b4 = ((const float4*)beta)[lane];
    int c0 = lane * 4;
    float4 rwv[8];
#pragma unroll
    for (int j = 0; j < 4; ++j) {
        rwv[j * 2]     = *(const float4*)(rw + (size_t)(c0 + j) * 8);
        rwv[j * 2 + 1] = *(const float4*)(rw + (size_t)(c0 + j) * 8 + 4);
    }

#pragma unroll
    for (int k = 0; k < 4; ++k) {
        int tl = w * 4 + k;
        float4 v = *(const float4*)&acc[tl][lane * 4];
        float s = v.x + v.y + v.z + v.w;
        float q = v.x * v.x + v.y * v.y + v.z * v.z + v.w * v.w;
#pragma unroll
        for (int m = 1; m < 64; m <<= 1) { s += __shfl_xor(s, m); q += __shfl_xor(q, m); }
        float mean = s * (1.0f / 256.0f);
        float var  = q * (1.0f / 256.0f) - mean * mean;
        float rstd = rsqrtf(var + 1e-6f);

        float xn[4];
        xn[0] = (v.x - mean) * rstd * g4.x + b4.x;
        xn[1] = (v.y - mean) * rstd * g4.y + b4.y;
        xn[2] = (v.z - mean) * rstd * g4.z + b4.z;
        xn[3] = (v.w - mean) * rstd * g4.w + b4.w;

        unsigned px = pk8_lo(xn[0], xn[1], 0u);
        px = pk8_hi(xn[2], xn[3], px);
        int tok = n * 1024 + y * 32 + tl;
        xf8[tok * 64 + lane] = px;

        float p[8];
#pragma unroll
        for (int e = 0; e < 8; ++e) p[e] = 0.f;
#pragma unroll
        for (int j = 0; j < 4; ++j) {
            float xv = xn[j];
            const float* r0 = (const float*)&rwv[j * 2];
#pragma unroll
            for (int e = 0; e < 8; ++e) p[e] += xv * r0[e];
        }
#pragma unroll
        for (int m = 1; m < 64; m <<= 1) {
#pragma unroll
            for (int e = 0; e < 8; ++e) p[e] += __shfl_xor(p[e], m);
        }
        if (lane == 0) {
            int e0 = 0; float l0 = p[0];
#pragma unroll
            for (int e = 1; e < 8; ++e) if (p[e] > l0) { l0 = p[e]; e0 = e; }
            int e1 = -1; float l1 = -3.4e38f;
#pragma unroll
            for (int e = 0; e < 8; ++e) if (e != e0 && p[e] > l1) { l1 = p[e]; e1 = e; }
            float tt = expf(l1 - l0);
            float w0 = 1.0f / (1.0f + tt);
            e01[tok] = e0 | (e1 << 8);
            gates[tok] = make_float2(w0, 1.0f - w0);
        }
    }
}

// Hierarchical capacity assignment.
__global__ __launch_bounds__(256) void k_assign(const int* __restrict__ e01,
                                                int* __restrict__ cnt,
                                                int* __restrict__ row_token,
                                                int2* __restrict__ slots) {
    __shared__ int lcnt[8];
    __shared__ int base[8];
    int t = threadIdx.x;
    if (t < 8) lcnt[t] = 0;
    __syncthreads();
    int tok = blockIdx.x * 256 + t;
    int ee = e01[tok];
    int e0 = ee & 255, e1 = (ee >> 8) & 255;
    int lp0 = atomicAdd(&lcnt[e0], 1);
    int lp1 = atomicAdd(&lcnt[e1], 1);
    __syncthreads();
    if (t < 8) base[t] = atomicAdd(cnt + t * CNT_STRIDE, lcnt[t]);
    __syncthreads();
    int pos0 = base[e0] + lp0;
    int pos1 = base[e1] + lp1;
    int slot0 = (pos0 < BE) ? e0 * BE + pos0 : -1;
    int slot1 = (pos1 < BE) ? e1 * BE + pos1 : -1;
    if (slot0 >= 0) row_token[slot0] = tok;
    if (slot1 >= 0) row_token[slot1] = tok;
    slots[tok] = make_int2(slot0, slot1);
}

// Transpose R x S (f32) -> S x R (fp8 e4m3), one matrix per blockIdx.z.
__global__ __launch_bounds__(256) void k_transpose8(const float* __restrict__ in,
                                                    unsigned char* __restrict__ out,
                                                    int R, int S) {
    __shared__ float tile[32][33];
    in += (size_t)blockIdx.z * R * S;
    out += (size_t)blockIdx.z * R * S;
    int tx = threadIdx.x & 31, ty = threadIdx.x >> 5;
    int sc = blockIdx.x * 32 + tx;
#pragma unroll
    for (int i = 0; i < 4; ++i) {
        int r = blockIdx.y * 32 + ty + i * 8;
        tile[ty + i * 8][tx] = in[(size_t)r * S + sc];
    }
    __syncthreads();
    int s = blockIdx.x * 32 + tx;
    int r0 = blockIdx.y * 32 + ty * 4;
    float v0 = tile[ty * 4 + 0][tx], v1 = tile[ty * 4 + 1][tx];
    float v2 = tile[ty * 4 + 2][tx], v3 = tile[ty * 4 + 3][tx];
    unsigned pk = pk8_lo(v0, v1, 0u);
    pk = pk8_hi(v2, v3, pk);
    *(unsigned*)(out + (size_t)s * R + r0) = pk;
}

// Fused expert MLP v3: 1024 threads (16 waves), 128 rows/block, e = bid&7.
// X in VGPRs (direct global). W1/W2 triple-buffered LDS via source-permuted
// global_load_lds; H double-buffered. Counted vmcnt + raw s_barrier (T3+T4):
// weight stages get 2 full barrier-intervals of latency slack.
__global__ __launch_bounds__(1024, 4) void k_mlp(const unsigned char* __restrict__ xf8,
                                                 const unsigned char* __restrict__ w1t8, // [E][1024][256]
                                                 const unsigned char* __restrict__ w2t8, // [E][256][1024]
                                                 const float* __restrict__ b1,
                                                 const float* __restrict__ b2,
                                                 const int* __restrict__ cnt,
                                                 const int* __restrict__ row_token,
                                                 unsigned short* __restrict__ Y) {
    int bid = blockIdx.x;
    int e = bid & 7;
    int row0 = (bid >> 3) * 128;
    int nrows = min(cnt[e * CNT_STRIDE], BE);
    if (row0 >= nrows) return;

    // LDS: W1 3x[64][272]=52224 | W2 3x[256][80]=61440 | H 2x[128][80]=20480
    __shared__ char smem[134144];
    __shared__ int tokl[128];
    char* const W1B[3] = {smem, smem + 17408, smem + 34816};
    char* const W2B[3] = {smem + 52224, smem + 72704, smem + 93184};
    char* const HB[2]  = {smem + 113664, smem + 123904};
    char* Ystage = smem;   // 64KB epilogue staging (aliases W areas)

    int t = threadIdx.x;
    int w = t >> 6, lane = t & 63;
    int l15 = lane & 15, l4 = lane >> 4;

    const unsigned char* w1e = w1t8 + (size_t)e * HIDN * 256;
    const unsigned char* w2e = w2t8 + (size_t)e * 256 * HIDN;

    // source-permuted staging offsets (pad slots point at c=0, never read)
    int w1s0, w1s1, w2s0, w2s1;
    {
        int p = w * 64 + lane, r = p / 17, c = p % 17; if (c == 16) c = 0;
        w1s0 = r * 256 + c * 16;
        int p1 = 1024 + lane; r = p1 / 17; c = p1 % 17; if (c == 16) c = 0;
        w1s1 = r * 256 + c * 16;
        p = w * 64 + lane; r = p / 5; c = p % 5; if (c == 4) c = 0;
        w2s0 = r * 1024 + c * 16;
        p1 = 1024 + w * 64 + lane; r = p1 / 5; c = p1 % 5; if (c == 4) c = 0;
        w2s1 = r * 1024 + c * 16;
    }
    auto StageW1 = [&](int hc, char* dst) {
        const unsigned char* g = w1e + hc * 16384;
        GL16(g + w1s0, dst + w * 1024);
        if (w == 0) GL16(g + w1s1, dst + 16384);
    };
    auto StageW2 = [&](int hc, char* dst) {
        const unsigned char* g = w2e + hc * 64;
        GL16(g + w2s0, dst + w * 1024);
        if (w < 4) GL16(g + w2s1, dst + 16384 + w * 1024);
    };

    if (t < 128) tokl[t] = (row0 + t < nrows) ? row_token[e * BE + row0 + t] : 0;
    __syncthreads();

    int hg = w & 3, tg = w >> 2;   // A-part role: hid 16-group, token 32-group
    int t16 = w & 7, oh = w >> 3;  // B-part role: token 16-group, out 128-half

    // X -> regs: 2 tok-frags x 8 k-slices, direct from global (L2/L3)
    long xr[2][8];
#pragma unroll
    for (int tf = 0; tf < 2; ++tf)
#pragma unroll
        for (int ks = 0; ks < 8; ++ks) {
            int row = tg * 32 + tf * 16 + l15;
            xr[tf][ks] = *(const long*)(xf8 + (size_t)tokl[row] * 256 + ks * 32 + l4 * 8);
        }

    f32x4 yacc[8];
#pragma unroll
    for (int nc = 0; nc < 8; ++nc) yacc[nc] = f32x4{0.f, 0.f, 0.f, 0.f};

    auto Apart = [&](int hc, const char* W1c, char* Hc) {
        long w1f[8];
#pragma unroll
        for (int ks = 0; ks < 8; ++ks)
            w1f[ks] = *(const long*)(W1c + (hg * 16 + l15) * 272 + ks * 32 + l4 * 8);
        f32x4 ha[2];
        ha[0] = f32x4{0.f, 0.f, 0.f, 0.f};
        ha[1] = f32x4{0.f, 0.f, 0.f, 0.f};
#pragma unroll
        for (int ks = 0; ks < 8; ++ks) {
            ha[0] = mfma8(w1f[ks], xr[0][ks], ha[0]);
            ha[1] = mfma8(w1f[ks], xr[1][ks], ha[1]);
        }
        float4 bb = *(const float4*)(b1 + e * HIDN + hc * 64 + hg * 16 + l4 * 4);
#pragma unroll
        for (int tf = 0; tf < 2; ++tf) {
            float g[4];
#pragma unroll
            for (int j = 0; j < 4; ++j) {
                float vv = ha[tf][j] + ((const float*)&bb)[j];
                float tt = vv * (1.0f + 0.044715f * vv * vv);
                g[j] = vv * __builtin_amdgcn_rcpf(1.0f + __builtin_amdgcn_exp2f(-2.3022100f * tt));
            }
            unsigned pk = pk8_lo(g[0], g[1], 0u);
            pk = pk8_hi(g[2], g[3], pk);
            int tok = tg * 32 + tf * 16 + l15;
            *(unsigned*)(Hc + tok * 80 + hg * 16 + l4 * 4) = pk;
        }
    };

    auto Bpart = [&](const char* W2c, const char* Hp) {
        long ah[2];
#pragma unroll
        for (int ks = 0; ks < 2; ++ks)
            ah[ks] = *(const long*)(Hp + (t16 * 16 + l15) * 80 + ks * 32 + l4 * 8);
#pragma unroll
        for (int nc = 0; nc < 8; ++nc) {
#pragma unroll
            for (int ks = 0; ks < 2; ++ks) {
                long w2f = *(const long*)(W2c + (oh * 128 + nc * 16 + l15) * 80 + ks * 32 + l4 * 8);
                yacc[nc] = mfma8(ah[ks], w2f, yacc[nc]);
            }
        }
    };

    // prologue: stage W1(0), W1(1), W2(0); full drain once.
    StageW1(0, W1B[0]);
    StageW1(1, W1B[1]);
    StageW2(0, W2B[0]);
    __builtin_amdgcn_sched_barrier(0);
    asm volatile("s_waitcnt vmcnt(0) lgkmcnt(0)" ::: "memory");
    __builtin_amdgcn_s_barrier();
    __builtin_amdgcn_sched_barrier(0);

#pragma unroll
    for (int hc = 0; hc < 16; ++hc) {
        if (hc + 2 < 16) StageW1(hc + 2, W1B[(hc + 2) % 3]);
        if (hc + 1 < 16) StageW2(hc + 1, W2B[(hc + 1) % 3]);
        Apart(hc, W1B[hc % 3], HB[hc & 1]);
        if (hc > 0) Bpart(W2B[(hc - 1) % 3], HB[(hc - 1) & 1]);
        __builtin_amdgcn_sched_barrier(0);
        if (hc < 14) {
            // leave this iteration's stages (V[w]) in flight; previous done
            if (w == 0)      asm volatile("s_waitcnt vmcnt(4) lgkmcnt(0)" ::: "memory");
            else if (w < 4)  asm volatile("s_waitcnt vmcnt(3) lgkmcnt(0)" ::: "memory");
            else             asm volatile("s_waitcnt vmcnt(2) lgkmcnt(0)" ::: "memory");
        } else {
            asm volatile("s_waitcnt vmcnt(0) lgkmcnt(0)" ::: "memory");
        }
        __builtin_amdgcn_s_barrier();
        __builtin_amdgcn_sched_barrier(0);
    }
    Bpart(W2B[0], HB[1]);   // hid chunk 15
    __syncthreads();

    // stage Y (+b2, ->bf16) into Ystage [128][512B], then coalesced copy-out
#pragma unroll
    for (int nc = 0; nc < 8; ++nc) {
        int col = oh * 128 + nc * 16 + l15;
        float b2v = b2[e * 256 + col];
#pragma unroll
        for (int j = 0; j < 4; ++j) {
            int tok = t16 * 16 + l4 * 4 + j;
            *(unsigned short*)(Ystage + tok * 512 + col * 2) = f2bf(yacc[nc][j] + b2v);
        }
    }
    __syncthreads();
    {
        char* Yg = (char*)(Y + ((size_t)e * BE + row0) * 256);
#pragma unroll
        for (int i = 0; i < 4; ++i) {
            int flat = i * 16384 + t * 16;
            *(int4*)(Yg + flat) = *(const int4*)(Ystage + flat);
        }
    }
}

// Gather expert outputs (bf16), gate, add residual, write NCHW.
__global__ __launch_bounds__(256) void k_gather(const float* __restrict__ input,
                                                const unsigned short* __restrict__ Y,
                                                const int2* __restrict__ slots,
                                                const float2* __restrict__ gates,
                                                const float* __restrict__ ls,
                                                float* __restrict__ out) {
    __shared__ float acc[32][257];
    int t = threadIdx.x;
    int n = blockIdx.x >> 5, y = blockIdx.x & 31;

    {
        int tl = t & 31, chunk = t >> 5;
        int tok = n * 1024 + y * 32 + tl;
        int2  sl = slots[tok];
        float2 gw = gates[tok];
        int c0 = chunk * 32;
#pragma unroll
        for (int i = 0; i < 4; ++i) {
            int c = c0 + i * 8;
            float v[8];
#pragma unroll
            for (int k = 0; k < 8; ++k) v[k] = 0.f;
            if (sl.x >= 0) {
                bf16x8 yv = *(const bf16x8*)(Y + (size_t)sl.x * 256 + c);
#pragma unroll
                for (int k = 0; k < 8; ++k) v[k] += gw.x * bf2f((unsigned short)yv[k]);
            }
            if (sl.y >= 0) {
                bf16x8 yv = *(const bf16x8*)(Y + (size_t)sl.y * 256 + c);
#pragma unroll
                for (int k = 0; k < 8; ++k) v[k] += gw.y * bf2f((unsigned short)yv[k]);
            }
#pragma unroll
            for (int k = 0; k < 8; ++k) acc[tl][c + k] = v[k];
        }
    }
    __syncthreads();
    {
        int x = t & 31, c8 = t >> 5;
        size_t base = (size_t)n * 256 * 1024 + (size_t)y * 32 + x;
#pragma unroll
        for (int p = 0; p < 32; ++p) {
            int c = p * 8 + c8;
            size_t id = base + (size_t)c * 1024;
            out[id] = input[id] + ls[c] * acc[x][c];
        }
    }
}

extern "C" void kernel_launch(void* const* d_in, const int* in_sizes, int n_in,
                              void* d_out, int out_size, void* d_ws, size_t ws_size,
                              hipStream_t stream) {
    const float* input = (const float*)d_in[0];
    const float* dwk   = (const float*)d_in[1];
    const float* dwb   = (const float*)d_in[2];
    const float* gamma = (const float*)d_in[3];
    const float* beta  = (const float*)d_in[4];
    const float* rw    = (const float*)d_in[5];
    const float* w1    = (const float*)d_in[6];
    const float* b1    = (const float*)d_in[7];
    const float* w2    = (const float*)d_in[8];
    const float* b2    = (const float*)d_in[9];
    const float* ls    = (const float*)d_in[10];

    char* ws = (char*)d_ws;
    // xcb (64MiB bf16 NCHW conv out) aliases Yb (40MiB): xcb dead before k_mlp writes Yb.
    unsigned short* xcb  = (unsigned short*)ws;
    unsigned short* Yb   = (unsigned short*)ws;
    unsigned*       xf8  = (unsigned*)(ws + 83886080);         // 8MB fp8 x
    unsigned char*  w1t8 = (unsigned char*)(ws + 100663296);   // 2MB
    unsigned char*  w2t8 = (unsigned char*)(ws + 104857600);   // 2MB
    int*            rtok = (int*)(ws + 109051904);             // 320KB
    int2*           slots = (int2*)(ws + 109379584);           // 256KB
    float2*         gates = (float2*)(ws + 109641728);         // 256KB
    int*            e01  = (int*)(ws + 109903872);             // 128KB
    int*            cnt  = (int*)(ws + 110035968);             // 8*64 ints

    k_init<<<1, NE * CNT_STRIDE, 0, stream>>>(cnt);
    k_conv<<<8192, 256, 0, stream>>>(input, dwk, dwb, xcb);
    k_lnr<<<1024, 512, 0, stream>>>(xcb, gamma, beta, rw, xf8, e01, gates);
    k_assign<<<128, 256, 0, stream>>>(e01, cnt, rtok, slots);
    k_transpose8<<<dim3(32, 8, 8), 256, 0, stream>>>(w1, w1t8, 256, 1024);  // [E][1024][256]
    k_transpose8<<<dim3(8, 32, 8), 256, 0, stream>>>(w2, w2t8, 1024, 256);  // [E][256][1024]
    k_mlp<<<640, 1024, 0, stream>>>((const unsigned char*)xf8, w1t8, w2t8, b1, b2, cnt, rtok, Yb);
    k_gather<<<1024, 256, 0, stream>>>(input, Yb, slots, gates, ls, (float*)d_out);
}

// Round 11
// 214.759 us; speedup vs baseline: 1.1104x; 1.1104x over previous
//
#include <hip/hip_runtime.h>
#include <math.h>

#define TOK 32768
#define CH  256
#define HIDN 1024
#define NE  8
#define BE  10240
#define CNT_STRIDE 64

typedef __attribute__((ext_vector_type(8))) short bf16x8;
typedef __attribute__((ext_vector_type(4))) float f32x4;

__device__ __forceinline__ unsigned short f2bf(float f) {
    unsigned u = __builtin_bit_cast(unsigned, f);
    unsigned r = 0x7FFFu + ((u >> 16) & 1u);
    return (unsigned short)((u + r) >> 16);
}
__device__ __forceinline__ float bf2f(unsigned short u) {
    return __builtin_bit_cast(float, (unsigned)u << 16);
}
__device__ __forceinline__ unsigned pk8_lo(float a, float b, unsigned old) {
    return (unsigned)__builtin_amdgcn_cvt_pk_fp8_f32(a, b, (int)old, false);
}
__device__ __forceinline__ unsigned pk8_hi(float a, float b, unsigned old) {
    return (unsigned)__builtin_amdgcn_cvt_pk_fp8_f32(a, b, (int)old, true);
}
__device__ __forceinline__ f32x4 mfma8(long a, long b, f32x4 c) {
    return __builtin_amdgcn_mfma_f32_16x16x32_fp8_fp8(a, b, c, 0, 0, 0);
}

typedef __attribute__((address_space(3))) void lds_t;
typedef const __attribute__((address_space(1))) void gm_t;
#define GL16(gp, lp) __builtin_amdgcn_global_load_lds((gm_t*)(gp), (lds_t*)(lp), 16, 0, 0)

__global__ void k_init(int* cnt) { cnt[threadIdx.x] = 0; }

// Depthwise 7x7 conv + bias. Block = one (n,c) image staged to LDS; each thread
// computes a 4-output vertical column. Output NCHW bf16, fully coalesced.
__global__ __launch_bounds__(256) void k_conv(const float* __restrict__ in,
                                              const float* __restrict__ kern,
                                              const float* __restrict__ bias,
                                              unsigned short* __restrict__ xcb) {
    __shared__ float img[1024];
    __shared__ float kwl[49];
    int t = threadIdx.x;
    int bid = blockIdx.x;          // bid = n*256 + c
    int c = bid & 255;

    GL16(in + (size_t)bid * 1024 + t * 4, (char*)img + t * 16);
    if (t < 49) kwl[t] = kern[c * 49 + t];
    __syncthreads();

    int x = t & 31, y0 = (t >> 5) * 4;
    float b0 = bias[c];
    float acc[4] = {b0, b0, b0, b0};
#pragma unroll
    for (int rr = 0; rr < 10; ++rr) {
        int r = y0 - 3 + rr;
        if ((unsigned)r < 32u) {
#pragma unroll
            for (int dx = -3; dx <= 3; ++dx) {
                int xx = x + dx;
                if ((unsigned)xx < 32u) {
                    float v = img[r * 32 + xx];
#pragma unroll
                    for (int o = 0; o < 4; ++o) {
                        int jr = rr - o;
                        if (0 <= jr && jr <= 6)
                            acc[o] = fmaf(v, kwl[jr * 7 + (dx + 3)], acc[o]);
                    }
                }
            }
        }
    }
#pragma unroll
    for (int o = 0; o < 4; ++o)
        xcb[(size_t)bid * 1024 + (y0 + o) * 32 + x] = f2bf(acc[o]);
}

// LN + router: block = (n,y) row. Coalesced bf16 loads, LDS transpose, wave LN.
__global__ __launch_bounds__(512) void k_lnr(const unsigned short* __restrict__ xcb,
                                             const float* __restrict__ gamma,
                                             const float* __restrict__ beta,
                                             const float* __restrict__ rw,
                                             unsigned* __restrict__ xf8,
                                             int* __restrict__ e01,
                                             float2* __restrict__ gates) {
    __shared__ float acc[32][260];
    int t = threadIdx.x;
    int n = blockIdx.x >> 5, y = blockIdx.x & 31;
    int x = t & 31, ch = t >> 5;

    float vals[16];
#pragma unroll
    for (int i = 0; i < 16; ++i) {
        int c = i * 16 + ch;
        vals[i] = bf2f(xcb[((size_t)(n * 256 + c)) * 1024 + y * 32 + x]);
    }
#pragma unroll
    for (int i = 0; i < 16; ++i) acc[x][i * 16 + ch] = vals[i];
    __syncthreads();

    int lane = t & 63, w = t >> 6;
    float4 g4 = ((const float4*)gamma)[lane];
    float4 b4 = ((const float4*)beta)[lane];
    int c0 = lane * 4;
    float4 rwv[8];
#pragma unroll
    for (int j = 0; j < 4; ++j) {
        rwv[j * 2]     = *(const float4*)(rw + (size_t)(c0 + j) * 8);
        rwv[j * 2 + 1] = *(const float4*)(rw + (size_t)(c0 + j) * 8 + 4);
    }

#pragma unroll
    for (int k = 0; k < 4; ++k) {
        int tl = w * 4 + k;
        float4 v = *(const float4*)&acc[tl][lane * 4];
        float s = v.x + v.y + v.z + v.w;
        float q = v.x * v.x + v.y * v.y + v.z * v.z + v.w * v.w;
#pragma unroll
        for (int m = 1; m < 64; m <<= 1) { s += __shfl_xor(s, m); q += __shfl_xor(q, m); }
        float mean = s * (1.0f / 256.0f);
        float var  = q * (1.0f / 256.0f) - mean * mean;
        float rstd = rsqrtf(var + 1e-6f);

        float xn[4];
        xn[0] = (v.x - mean) * rstd * g4.x + b4.x;
        xn[1] = (v.y - mean) * rstd * g4.y + b4.y;
        xn[2] = (v.z - mean) * rstd * g4.z + b4.z;
        xn[3] = (v.w - mean) * rstd * g4.w + b4.w;

        unsigned px = pk8_lo(xn[0], xn[1], 0u);
        px = pk8_hi(xn[2], xn[3], px);
        int tok = n * 1024 + y * 32 + tl;
        xf8[tok * 64 + lane] = px;

        float p[8];
#pragma unroll
        for (int e = 0; e < 8; ++e) p[e] = 0.f;
#pragma unroll
        for (int j = 0; j < 4; ++j) {
            float xv = xn[j];
            const float* r0 = (const float*)&rwv[j * 2];
#pragma unroll
            for (int e = 0; e < 8; ++e) p[e] += xv * r0[e];
        }
#pragma unroll
        for (int m = 1; m < 64; m <<= 1) {
#pragma unroll
            for (int e = 0; e < 8; ++e) p[e] += __shfl_xor(p[e], m);
        }
        if (lane == 0) {
            int e0 = 0; float l0 = p[0];
#pragma unroll
            for (int e = 1; e < 8; ++e) if (p[e] > l0) { l0 = p[e]; e0 = e; }
            int e1 = -1; float l1 = -3.4e38f;
#pragma unroll
            for (int e = 0; e < 8; ++e) if (e != e0 && p[e] > l1) { l1 = p[e]; e1 = e; }
            float tt = expf(l1 - l0);
            float w0 = 1.0f / (1.0f + tt);
            e01[tok] = e0 | (e1 << 8);
            gates[tok] = make_float2(w0, 1.0f - w0);
        }
    }
}

// Hierarchical capacity assignment.
__global__ __launch_bounds__(256) void k_assign(const int* __restrict__ e01,
                                                int* __restrict__ cnt,
                                                int* __restrict__ row_token,
                                                int2* __restrict__ slots) {
    __shared__ int lcnt[8];
    __shared__ int base[8];
    int t = threadIdx.x;
    if (t < 8) lcnt[t] = 0;
    __syncthreads();
    int tok = blockIdx.x * 256 + t;
    int ee = e01[tok];
    int e0 = ee & 255, e1 = (ee >> 8) & 255;
    int lp0 = atomicAdd(&lcnt[e0], 1);
    int lp1 = atomicAdd(&lcnt[e1], 1);
    __syncthreads();
    if (t < 8) base[t] = atomicAdd(cnt + t * CNT_STRIDE, lcnt[t]);
    __syncthreads();
    int pos0 = base[e0] + lp0;
    int pos1 = base[e1] + lp1;
    int slot0 = (pos0 < BE) ? e0 * BE + pos0 : -1;
    int slot1 = (pos1 < BE) ? e1 * BE + pos1 : -1;
    if (slot0 >= 0) row_token[slot0] = tok;
    if (slot1 >= 0) row_token[slot1] = tok;
    slots[tok] = make_int2(slot0, slot1);
}

// Pack W1 [E][C=256][H=1024] f32 -> MFMA-native A-operand tiles, fp8.
// Tile (e, hr, ks): lane l holds 8 bytes: row = hr*16+(l&15) (hid),
// k = ks*32+(l>>4)*8+b (channel). Tile = 512B, flat [e][hr][ks][l*8].
__global__ __launch_bounds__(256) void k_pack_w1(const float* __restrict__ w1,
                                                 unsigned char* __restrict__ w1p) {
    int s = blockIdx.x * 256 + threadIdx.x;
    int l = s & 63, tile = s >> 6;
    int ks = tile & 7, hr = (tile >> 3) & 63, e = tile >> 9;
    int l15 = l & 15, l4 = l >> 4;
    const float* src = w1 + ((size_t)e * 256 + ks * 32 + l4 * 8) * 1024 + hr * 16 + l15;
    float v[8];
#pragma unroll
    for (int b = 0; b < 8; ++b) v[b] = src[b * 1024];
    unsigned lo = pk8_hi(v[2], v[3], pk8_lo(v[0], v[1], 0u));
    unsigned hi = pk8_hi(v[6], v[7], pk8_lo(v[4], v[5], 0u));
    *(uint2*)(w1p + (size_t)tile * 512 + l * 8) = make_uint2(lo, hi);
}

// Pack W2 [E][H=1024][C=256] f32 -> MFMA-native B-operand tiles, fp8.
// Tile (e, hk, orow): lane l: col = orow*16+(l&15) (out ch),
// k = hk*32+(l>>4)*8+b (hid). Flat [e][hk][orow][l*8].
__global__ __launch_bounds__(256) void k_pack_w2(const float* __restrict__ w2,
                                                 unsigned char* __restrict__ w2p) {
    int s = blockIdx.x * 256 + threadIdx.x;
    int l = s & 63, tile = s >> 6;
    int orow = tile & 15, hk = (tile >> 4) & 31, e = tile >> 9;
    int l15 = l & 15, l4 = l >> 4;
    const float* src = w2 + ((size_t)e * 1024 + hk * 32 + l4 * 8) * 256 + orow * 16 + l15;
    float v[8];
#pragma unroll
    for (int b = 0; b < 8; ++b) v[b] = src[b * 256];
    unsigned lo = pk8_hi(v[2], v[3], pk8_lo(v[0], v[1], 0u));
    unsigned hi = pk8_hi(v[6], v[7], pk8_lo(v[4], v[5], 0u));
    *(uint2*)(w2p + (size_t)tile * 512 + l * 8) = make_uint2(lo, hi);
}

// Fused expert MLP v4: 256 threads (4 waves), 128 rows/block, e = bid&7.
// Wave owns 32 tokens end-to-end: A (W1@X -> H, lane=token layout), gelu,
// in-register quad-exchange -> H as A-operand, B (H@W2) -- no H LDS, no A/B
// barrier. Weights in MFMA-native tiles, triple-buffered LDS (GL16), one
// barrier + counted vmcnt(4) per 32-hid step. X and yacc live in VGPRs.
__global__ __launch_bounds__(256, 2) void k_mlp(const unsigned char* __restrict__ xf8,
                                                const unsigned char* __restrict__ w1p,
                                                const unsigned char* __restrict__ w2p,
                                                const float* __restrict__ b1,
                                                const float* __restrict__ b2,
                                                const int* __restrict__ cnt,
                                                const int* __restrict__ row_token,
                                                unsigned short* __restrict__ Y) {
    int bid = blockIdx.x;
    int e = bid & 7;
    int row0 = (bid >> 3) * 128;
    int nrows = min(cnt[e * CNT_STRIDE], BE);
    if (row0 >= nrows) return;

    // smem: 3 x 16KB W-slots (W1 8KB | W2 8KB) + 4KB b1; Ystage 64KB aliases.
    __shared__ char smem[65536];
    char* b1lds = smem + 49152;

    int t = threadIdx.x;
    int w = t >> 6, lane = t & 63;
    int l15 = lane & 15, l4 = lane >> 4;

    const unsigned char* w1e = w1p + (size_t)e * 262144;
    const unsigned char* w2e = w2p + (size_t)e * 262144;

    auto StageW = [&](int hc, char* dst) {
        const unsigned char* g1 = w1e + hc * 8192;
        const unsigned char* g2 = w2e + hc * 8192;
        GL16(g1 + t * 16, dst + t * 16);
        GL16(g1 + 4096 + t * 16, dst + 4096 + t * 16);
        GL16(g2 + t * 16, dst + 8192 + t * 16);
        GL16(g2 + 4096 + t * 16, dst + 12288 + t * 16);
    };

    // token ids for this wave's 32 rows (2 x 16-row frags)
    int tok[2];
#pragma unroll
    for (int tf = 0; tf < 2; ++tf) {
        int r = row0 + w * 32 + tf * 16 + l15;
        tok[tf] = (r < nrows) ? row_token[e * BE + r] : 0;
    }
    // X -> VGPR: 2 tf x 8 ks b64 frags
    long xr[2][8];
#pragma unroll
    for (int tf = 0; tf < 2; ++tf)
#pragma unroll
        for (int ks = 0; ks < 8; ++ks)
            xr[tf][ks] = *(const long*)(xf8 + (size_t)tok[tf] * 256 + ks * 32 + l4 * 8);

    // stage b1 slice (4KB) + W slots 0,1
    GL16((const char*)(b1 + e * HIDN) + t * 16, b1lds + t * 16);
    StageW(0, smem);
    StageW(1, smem + 16384);
    __builtin_amdgcn_sched_barrier(0);
    asm volatile("s_waitcnt vmcnt(4)" ::: "memory");   // X, b1, slot0 landed; slot1 in flight
    __builtin_amdgcn_s_barrier();
    __builtin_amdgcn_sched_barrier(0);

    f32x4 yacc[2][16];
#pragma unroll
    for (int tf = 0; tf < 2; ++tf)
#pragma unroll
        for (int nc = 0; nc < 16; ++nc) yacc[tf][nc] = f32x4{0.f, 0.f, 0.f, 0.f};

    int cur = 0, nxt = 1, fr = 2;
    for (int hc = 0; hc < 32; ++hc) {
        if (hc + 2 < 32) StageW(hc + 2, smem + fr * 16384);
        const char* Wc = smem + cur * 16384;

        // ---- A: ha[tf][h] = W1-tile(h) @ X(tf), C layout: col=token, row=hid
        long w1f[2][8];
#pragma unroll
        for (int h = 0; h < 2; ++h)
#pragma unroll
            for (int ks = 0; ks < 8; ++ks)
                w1f[h][ks] = *(const long*)(Wc + (h * 8 + ks) * 512 + lane * 8);
        f32x4 ha[2][2];
#pragma unroll
        for (int tf = 0; tf < 2; ++tf)
#pragma unroll
            for (int h = 0; h < 2; ++h) ha[tf][h] = f32x4{0.f, 0.f, 0.f, 0.f};
#pragma unroll
        for (int ks = 0; ks < 8; ++ks)
#pragma unroll
            for (int h = 0; h < 2; ++h)
#pragma unroll
                for (int tf = 0; tf < 2; ++tf)
                    ha[tf][h] = mfma8(w1f[h][ks], xr[tf][ks], ha[tf][h]);

        // ---- gelu + pack + quad exchange -> hfrag[tf] (A-operand, k=32 hid)
        float4 b1v[2];
#pragma unroll
        for (int h = 0; h < 2; ++h)
            b1v[h] = *(const float4*)(b1lds + hc * 128 + h * 64 + l4 * 16);
        long hfrag[2];
#pragma unroll
        for (int tf = 0; tf < 2; ++tf) {
            unsigned p[2];
#pragma unroll
            for (int h = 0; h < 2; ++h) {
                float g[4];
#pragma unroll
                for (int j = 0; j < 4; ++j) {
                    float vv = ha[tf][h][j] + ((const float*)&b1v[h])[j];
                    float tt = vv * (1.0f + 0.044715f * vv * vv);
                    g[j] = vv * __builtin_amdgcn_rcpf(1.0f + __builtin_amdgcn_exp2f(-2.3022100f * tt));
                }
                p[h] = pk8_hi(g[2], g[3], pk8_lo(g[0], g[1], 0u));
            }
            int src0 = l15 + ((l4 & 1) * 2) * 16;
            int a0 = __shfl((int)p[0], src0);
            int a1 = __shfl((int)p[1], src0);
            int b0 = __shfl((int)p[0], src0 + 16);
            int b1_ = __shfl((int)p[1], src0 + 16);
            unsigned lo = (l4 < 2) ? (unsigned)a0 : (unsigned)a1;
            unsigned hi = (l4 < 2) ? (unsigned)b0 : (unsigned)b1_;
            hfrag[tf] = (long)(((unsigned long)hi << 32) | (unsigned long)lo);
        }

        // ---- B: yacc[tf][nc] += H(tf) @ W2-tile(nc)
#pragma unroll
        for (int nc = 0; nc < 16; ++nc) {
            long w2f = *(const long*)(Wc + 8192 + nc * 512 + lane * 8);
            yacc[0][nc] = mfma8(hfrag[0], w2f, yacc[0][nc]);
            yacc[1][nc] = mfma8(hfrag[1], w2f, yacc[1][nc]);
        }

        __builtin_amdgcn_sched_barrier(0);
        if (hc < 30) asm volatile("s_waitcnt vmcnt(4)" ::: "memory");
        else         asm volatile("s_waitcnt vmcnt(0)" ::: "memory");
        __builtin_amdgcn_s_barrier();
        __builtin_amdgcn_sched_barrier(0);
        int tmp = cur; cur = nxt; nxt = fr; fr = tmp;
    }

    // ---- epilogue: yacc (+b2, ->bf16) -> Ystage (aliases W slots), copy out.
    // yacc layout: col = l15 = out(nc*16+l15), row = token = tf*16 + l4*4 + j
    char* Ystage = smem;
#pragma unroll
    for (int nc = 0; nc < 16; ++nc) {
        float b2v = b2[e * 256 + nc * 16 + l15];
#pragma unroll
        for (int tf = 0; tf < 2; ++tf)
#pragma unroll
            for (int j = 0; j < 4; ++j) {
                int tokr = w * 32 + tf * 16 + l4 * 4 + j;
                *(unsigned short*)(Ystage + tokr * 512 + (nc * 16 + l15) * 2) =
                    f2bf(yacc[tf][nc][j] + b2v);
            }
    }
    __syncthreads();
    {
        char* Yg = (char*)(Y + ((size_t)e * BE + row0) * 256);
#pragma unroll
        for (int i = 0; i < 16; ++i) {
            int flat = i * 4096 + t * 16;
            *(int4*)(Yg + flat) = *(const int4*)(Ystage + flat);
        }
    }
}

// Gather expert outputs (bf16), gate, add residual, write NCHW.
__global__ __launch_bounds__(256) void k_gather(const float* __restrict__ input,
                                                const unsigned short* __restrict__ Y,
                                                const int2* __restrict__ slots,
                                                const float2* __restrict__ gates,
                                                const float* __restrict__ ls,
                                                float* __restrict__ out) {
    __shared__ float acc[32][257];
    int t = threadIdx.x;
    int n = blockIdx.x >> 5, y = blockIdx.x & 31;

    {
        int tl = t & 31, chunk = t >> 5;
        int tok = n * 1024 + y * 32 + tl;
        int2  sl = slots[tok];
        float2 gw = gates[tok];
        int c0 = chunk * 32;
#pragma unroll
        for (int i = 0; i < 4; ++i) {
            int c = c0 + i * 8;
            float v[8];
#pragma unroll
            for (int k = 0; k < 8; ++k) v[k] = 0.f;
            if (sl.x >= 0) {
                bf16x8 yv = *(const bf16x8*)(Y + (size_t)sl.x * 256 + c);
#pragma unroll
                for (int k = 0; k < 8; ++k) v[k] += gw.x * bf2f((unsigned short)yv[k]);
            }
            if (sl.y >= 0) {
                bf16x8 yv = *(const bf16x8*)(Y + (size_t)sl.y * 256 + c);
#pragma unroll
                for (int k = 0; k < 8; ++k) v[k] += gw.y * bf2f((unsigned short)yv[k]);
            }
#pragma unroll
            for (int k = 0; k < 8; ++k) acc[tl][c + k] = v[k];
        }
    }
    __syncthreads();
    {
        int x = t & 31, c8 = t >> 5;
        size_t base = (size_t)n * 256 * 1024 + (size_t)y * 32 + x;
#pragma unroll
        for (int p = 0; p < 32; ++p) {
            int c = p * 8 + c8;
            size_t id = base + (size_t)c * 1024;
            out[id] = input[id] + ls[c] * acc[x][c];
        }
    }
}

extern "C" void kernel_launch(void* const* d_in, const int* in_sizes, int n_in,
                              void* d_out, int out_size, void* d_ws, size_t ws_size,
                              hipStream_t stream) {
    const float* input = (const float*)d_in[0];
    const float* dwk   = (const float*)d_in[1];
    const float* dwb   = (const float*)d_in[2];
    const float* gamma = (const float*)d_in[3];
    const float* beta  = (const float*)d_in[4];
    const float* rw    = (const float*)d_in[5];
    const float* w1    = (const float*)d_in[6];
    const float* b1    = (const float*)d_in[7];
    const float* w2    = (const float*)d_in[8];
    const float* b2    = (const float*)d_in[9];
    const float* ls    = (const float*)d_in[10];

    char* ws = (char*)d_ws;
    // xcb (64MiB bf16 NCHW conv out) aliases Yb (40MiB): xcb dead before k_mlp writes Yb.
    unsigned short* xcb  = (unsigned short*)ws;
    unsigned short* Yb   = (unsigned short*)ws;
    unsigned*       xf8  = (unsigned*)(ws + 83886080);         // 8MB fp8 x
    unsigned char*  w1p  = (unsigned char*)(ws + 100663296);   // 2MB tiled fp8
    unsigned char*  w2p  = (unsigned char*)(ws + 104857600);   // 2MB tiled fp8
    int*            rtok = (int*)(ws + 109051904);             // 320KB
    int2*           slots = (int2*)(ws + 109379584);           // 256KB
    float2*         gates = (float2*)(ws + 109641728);         // 256KB
    int*            e01  = (int*)(ws + 109903872);             // 128KB
    int*            cnt  = (int*)(ws + 110035968);             // 8*64 ints

    k_init<<<1, NE * CNT_STRIDE, 0, stream>>>(cnt);
    k_conv<<<8192, 256, 0, stream>>>(input, dwk, dwb, xcb);
    k_lnr<<<1024, 512, 0, stream>>>(xcb, gamma, beta, rw, xf8, e01, gates);
    k_assign<<<128, 256, 0, stream>>>(e01, cnt, rtok, slots);
    k_pack_w1<<<1024, 256, 0, stream>>>(w1, w1p);
    k_pack_w2<<<1024, 256, 0, stream>>>(w2, w2p);
    k_mlp<<<640, 256, 0, stream>>>((const unsigned char*)xf8, w1p, w2p, b1, b2, cnt, rtok, Yb);
    k_gather<<<1024, 256, 0, stream>>>(input, Yb, slots, gates, ls, (float*)d_out);
}

// Round 12
// 195.003 us; speedup vs baseline: 1.2229x; 1.1013x over previous
//
#include <hip/hip_runtime.h>
#include <math.h>

#define TOK 32768
#define CH  256
#define HIDN 1024
#define NE  8
#define BE  10240
#define CNT_STRIDE 64

typedef __attribute__((ext_vector_type(8))) short bf16x8;
typedef __attribute__((ext_vector_type(4))) float f32x4;
typedef __attribute__((ext_vector_type(2))) long long2v;

__device__ __forceinline__ unsigned short f2bf(float f) {
    unsigned u = __builtin_bit_cast(unsigned, f);
    unsigned r = 0x7FFFu + ((u >> 16) & 1u);
    return (unsigned short)((u + r) >> 16);
}
__device__ __forceinline__ float bf2f(unsigned short u) {
    return __builtin_bit_cast(float, (unsigned)u << 16);
}
__device__ __forceinline__ unsigned pk8_lo(float a, float b, unsigned old) {
    return (unsigned)__builtin_amdgcn_cvt_pk_fp8_f32(a, b, (int)old, false);
}
__device__ __forceinline__ unsigned pk8_hi(float a, float b, unsigned old) {
    return (unsigned)__builtin_amdgcn_cvt_pk_fp8_f32(a, b, (int)old, true);
}
__device__ __forceinline__ f32x4 mfma8(long a, long b, f32x4 c) {
    return __builtin_amdgcn_mfma_f32_16x16x32_fp8_fp8(a, b, c, 0, 0, 0);
}

typedef __attribute__((address_space(3))) void lds_t;
typedef const __attribute__((address_space(1))) void gm_t;
#define GL16(gp, lp) __builtin_amdgcn_global_load_lds((gm_t*)(gp), (lds_t*)(lp), 16, 0, 0)

__global__ void k_init(int* cnt) { cnt[threadIdx.x] = 0; }

// Depthwise 7x7 conv + bias. Block = one (n,c) image staged to LDS; each thread
// computes a 4-output vertical column. Output NCHW bf16, fully coalesced.
__global__ __launch_bounds__(256) void k_conv(const float* __restrict__ in,
                                              const float* __restrict__ kern,
                                              const float* __restrict__ bias,
                                              unsigned short* __restrict__ xcb) {
    __shared__ float img[1024];
    __shared__ float kwl[49];
    int t = threadIdx.x;
    int bid = blockIdx.x;          // bid = n*256 + c
    int c = bid & 255;

    GL16(in + (size_t)bid * 1024 + t * 4, (char*)img + t * 16);
    if (t < 49) kwl[t] = kern[c * 49 + t];
    __syncthreads();

    int x = t & 31, y0 = (t >> 5) * 4;
    float b0 = bias[c];
    float acc[4] = {b0, b0, b0, b0};
#pragma unroll
    for (int rr = 0; rr < 10; ++rr) {
        int r = y0 - 3 + rr;
        if ((unsigned)r < 32u) {
#pragma unroll
            for (int dx = -3; dx <= 3; ++dx) {
                int xx = x + dx;
                if ((unsigned)xx < 32u) {
                    float v = img[r * 32 + xx];
#pragma unroll
                    for (int o = 0; o < 4; ++o) {
                        int jr = rr - o;
                        if (0 <= jr && jr <= 6)
                            acc[o] = fmaf(v, kwl[jr * 7 + (dx + 3)], acc[o]);
                    }
                }
            }
        }
    }
#pragma unroll
    for (int o = 0; o < 4; ++o)
        xcb[(size_t)bid * 1024 + (y0 + o) * 32 + x] = f2bf(acc[o]);
}

// LN + router: block = (n,y) row. Coalesced bf16 loads, LDS transpose, wave LN.
__global__ __launch_bounds__(512) void k_lnr(const unsigned short* __restrict__ xcb,
                                             const float* __restrict__ gamma,
                                             const float* __restrict__ beta,
                                             const float* __restrict__ rw,
                                             unsigned* __restrict__ xf8,
                                             int* __restrict__ e01,
                                             float2* __restrict__ gates) {
    __shared__ float acc[32][260];
    int t = threadIdx.x;
    int n = blockIdx.x >> 5, y = blockIdx.x & 31;
    int x = t & 31, ch = t >> 5;

    float vals[16];
#pragma unroll
    for (int i = 0; i < 16; ++i) {
        int c = i * 16 + ch;
        vals[i] = bf2f(xcb[((size_t)(n * 256 + c)) * 1024 + y * 32 + x]);
    }
#pragma unroll
    for (int i = 0; i < 16; ++i) acc[x][i * 16 + ch] = vals[i];
    __syncthreads();

    int lane = t & 63, w = t >> 6;
    float4 g4 = ((const float4*)gamma)[lane];
    float4 b4 = ((const float4*)beta)[lane];
    int c0 = lane * 4;
    float4 rwv[8];
#pragma unroll
    for (int j = 0; j < 4; ++j) {
        rwv[j * 2]     = *(const float4*)(rw + (size_t)(c0 + j) * 8);
        rwv[j * 2 + 1] = *(const float4*)(rw + (size_t)(c0 + j) * 8 + 4);
    }

#pragma unroll
    for (int k = 0; k < 4; ++k) {
        int tl = w * 4 + k;
        float4 v = *(const float4*)&acc[tl][lane * 4];
        float s = v.x + v.y + v.z + v.w;
        float q = v.x * v.x + v.y * v.y + v.z * v.z + v.w * v.w;
#pragma unroll
        for (int m = 1; m < 64; m <<= 1) { s += __shfl_xor(s, m); q += __shfl_xor(q, m); }
        float mean = s * (1.0f / 256.0f);
        float var  = q * (1.0f / 256.0f) - mean * mean;
        float rstd = rsqrtf(var + 1e-6f);

        float xn[4];
        xn[0] = (v.x - mean) * rstd * g4.x + b4.x;
        xn[1] = (v.y - mean) * rstd * g4.y + b4.y;
        xn[2] = (v.z - mean) * rstd * g4.z + b4.z;
        xn[3] = (v.w - mean) * rstd * g4.w + b4.w;

        unsigned px = pk8_lo(xn[0], xn[1], 0u);
        px = pk8_hi(xn[2], xn[3], px);
        int tok = n * 1024 + y * 32 + tl;
        xf8[tok * 64 + lane] = px;

        float p[8];
#pragma unroll
        for (int e = 0; e < 8; ++e) p[e] = 0.f;
#pragma unroll
        for (int j = 0; j < 4; ++j) {
            float xv = xn[j];
            const float* r0 = (const float*)&rwv[j * 2];
#pragma unroll
            for (int e = 0; e < 8; ++e) p[e] += xv * r0[e];
        }
#pragma unroll
        for (int m = 1; m < 64; m <<= 1) {
#pragma unroll
            for (int e = 0; e < 8; ++e) p[e] += __shfl_xor(p[e], m);
        }
        if (lane == 0) {
            int e0 = 0; float l0 = p[0];
#pragma unroll
            for (int e = 1; e < 8; ++e) if (p[e] > l0) { l0 = p[e]; e0 = e; }
            int e1 = -1; float l1 = -3.4e38f;
#pragma unroll
            for (int e = 0; e < 8; ++e) if (e != e0 && p[e] > l1) { l1 = p[e]; e1 = e; }
            float tt = expf(l1 - l0);
            float w0 = 1.0f / (1.0f + tt);
            e01[tok] = e0 | (e1 << 8);
            gates[tok] = make_float2(w0, 1.0f - w0);
        }
    }
}

// Hierarchical capacity assignment.
__global__ __launch_bounds__(256) void k_assign(const int* __restrict__ e01,
                                                int* __restrict__ cnt,
                                                int* __restrict__ row_token,
                                                int2* __restrict__ slots) {
    __shared__ int lcnt[8];
    __shared__ int base[8];
    int t = threadIdx.x;
    if (t < 8) lcnt[t] = 0;
    __syncthreads();
    int tok = blockIdx.x * 256 + t;
    int ee = e01[tok];
    int e0 = ee & 255, e1 = (ee >> 8) & 255;
    int lp0 = atomicAdd(&lcnt[e0], 1);
    int lp1 = atomicAdd(&lcnt[e1], 1);
    __syncthreads();
    if (t < 8) base[t] = atomicAdd(cnt + t * CNT_STRIDE, lcnt[t]);
    __syncthreads();
    int pos0 = base[e0] + lp0;
    int pos1 = base[e1] + lp1;
    int slot0 = (pos0 < BE) ? e0 * BE + pos0 : -1;
    int slot1 = (pos1 < BE) ? e1 * BE + pos1 : -1;
    if (slot0 >= 0) row_token[slot0] = tok;
    if (slot1 >= 0) row_token[slot1] = tok;
    slots[tok] = make_int2(slot0, slot1);
}

// Pack W1 [E][C=256][H=1024] f32 -> paired MFMA A-operand tiles, fp8.
// Tile (e,hc,h,kp): lane l holds 16B = frag(ks=2kp)[8B] | frag(ks=2kp+1)[8B];
// frag(ks): row hid = hc*32+h*16+(l&15), k ch = ks*32+(l>>4)*8+b.
__global__ __launch_bounds__(256) void k_pack_w1(const float* __restrict__ w1,
                                                 unsigned char* __restrict__ w1p) {
    int s = blockIdx.x * 256 + threadIdx.x;
    int l = s & 63, tile = s >> 6;
    int kp = tile & 3, h = (tile >> 2) & 1, hc = (tile >> 3) & 31, e = tile >> 8;
    int l15 = l & 15, l4 = l >> 4;
    int hid = hc * 32 + h * 16 + l15;
    int ch0 = kp * 64 + l4 * 8;
    const float* s0 = w1 + ((size_t)e * 256 + ch0) * 1024 + hid;
    float v[8], u[8];
#pragma unroll
    for (int b = 0; b < 8; ++b) { v[b] = s0[b * 1024]; u[b] = s0[(b + 32) * 1024]; }
    uint4 o;
    o.x = pk8_hi(v[2], v[3], pk8_lo(v[0], v[1], 0u));
    o.y = pk8_hi(v[6], v[7], pk8_lo(v[4], v[5], 0u));
    o.z = pk8_hi(u[2], u[3], pk8_lo(u[0], u[1], 0u));
    o.w = pk8_hi(u[6], u[7], pk8_lo(u[4], u[5], 0u));
    *(uint4*)(w1p + (size_t)tile * 1024 + l * 16) = o;
}

// Pack W2 [E][H=1024][C=256] f32 -> paired MFMA B-operand tiles, fp8.
// Tile (e,hc,np): lane l holds 16B = frag(nc=2np)[8B] | frag(nc=2np+1)[8B];
// frag(nc): col = nc*16+(l&15), k hid = hc*32+(l>>4)*8+b.
__global__ __launch_bounds__(256) void k_pack_w2(const float* __restrict__ w2,
                                                 unsigned char* __restrict__ w2p) {
    int s = blockIdx.x * 256 + threadIdx.x;
    int l = s & 63, tile = s >> 6;
    int np = tile & 7, hc = (tile >> 3) & 31, e = tile >> 8;
    int l15 = l & 15, l4 = l >> 4;
    int hid0 = hc * 32 + l4 * 8;
    int col0 = np * 32 + l15;
    const float* s0 = w2 + ((size_t)e * 1024 + hid0) * 256 + col0;
    float v[8], u[8];
#pragma unroll
    for (int b = 0; b < 8; ++b) { v[b] = s0[b * 256]; u[b] = s0[b * 256 + 16]; }
    uint4 o;
    o.x = pk8_hi(v[2], v[3], pk8_lo(v[0], v[1], 0u));
    o.y = pk8_hi(v[6], v[7], pk8_lo(v[4], v[5], 0u));
    o.z = pk8_hi(u[2], u[3], pk8_lo(u[0], u[1], 0u));
    o.w = pk8_hi(u[6], u[7], pk8_lo(u[4], u[5], 0u));
    *(uint4*)(w2p + (size_t)tile * 1024 + l * 16) = o;
}

// Fused expert MLP v5: 256 threads (4 waves), 128 rows/block, e = bid&7.
// Cross-step pipeline: during step s, B consumes hfrag(s-1)+W2(s-1) while
// gelu(s) runs on VALU -- independent streams inside one barrier region.
// W1 triple-buffered (3x8KB), W2 quad-buffered (4x8KB), counted vmcnt(6).
// Paired-frag W tiles: every W read is one contiguous ds_read_b128.
__global__ __launch_bounds__(256, 2) void k_mlp(const unsigned char* __restrict__ xf8,
                                                const unsigned char* __restrict__ w1p,
                                                const unsigned char* __restrict__ w2p,
                                                const float* __restrict__ b1,
                                                const float* __restrict__ b2,
                                                const int* __restrict__ cnt,
                                                const int* __restrict__ row_token,
                                                unsigned short* __restrict__ Y) {
    int bid = blockIdx.x;
    int e = bid & 7;
    int row0 = (bid >> 3) * 128;
    int nrows = min(cnt[e * CNT_STRIDE], BE);
    if (row0 >= nrows) return;

    __shared__ char smem[61440];
    char* const W1S0 = smem;
    char* const W1S1 = smem + 8192;
    char* const W1S2 = smem + 16384;
    char* const W2S0 = smem + 24576;
    char* const W2S1 = smem + 32768;
    char* const W2S2 = smem + 40960;
    char* const W2S3 = smem + 49152;
    char* const b1lds = smem + 57344;

    int t = threadIdx.x;
    int w = t >> 6, lane = t & 63;
    int l15 = lane & 15, l4 = lane >> 4;

    const unsigned char* w1e = w1p + (size_t)e * 262144;
    const unsigned char* w2e = w2p + (size_t)e * 262144;

    // tokens + X -> VGPR first (so later manual vmcnt slack is exact)
    int r0i = row0 + w * 32 + l15;
    int tok0 = (r0i < nrows) ? row_token[e * BE + r0i] : 0;
    int tok1 = (r0i + 16 < nrows) ? row_token[e * BE + r0i + 16] : 0;
    long xr[2][8];
#pragma unroll
    for (int ks = 0; ks < 8; ++ks) {
        xr[0][ks] = *(const long*)(xf8 + (size_t)tok0 * 256 + ks * 32 + l4 * 8);
        xr[1][ks] = *(const long*)(xf8 + (size_t)tok1 * 256 + ks * 32 + l4 * 8);
    }

    // b1 + prologue stages: W1(0),W2(0),W1(1),W2(1)
    GL16((const char*)(b1 + e * HIDN) + t * 16, b1lds + t * 16);
    GL16(w1e + t * 16, W1S0 + t * 16);
    GL16(w1e + 4096 + t * 16, W1S0 + 4096 + t * 16);
    GL16(w2e + t * 16, W2S0 + t * 16);
    GL16(w2e + 4096 + t * 16, W2S0 + 4096 + t * 16);
    GL16(w1e + 8192 + t * 16, W1S1 + t * 16);
    GL16(w1e + 12288 + t * 16, W1S1 + 4096 + t * 16);
    GL16(w2e + 8192 + t * 16, W2S1 + t * 16);
    GL16(w2e + 12288 + t * 16, W2S1 + 4096 + t * 16);
    __builtin_amdgcn_sched_barrier(0);
    asm volatile("s_waitcnt vmcnt(6)" ::: "memory");
    __builtin_amdgcn_s_barrier();
    __builtin_amdgcn_sched_barrier(0);

    f32x4 yacc[2][16];
#pragma unroll
    for (int tf = 0; tf < 2; ++tf)
#pragma unroll
        for (int nc = 0; nc < 16; ++nc) yacc[tf][nc] = f32x4{0.f, 0.f, 0.f, 0.f};

    long hfA0 = 0, hfA1 = 0, hfB0 = 0, hfB1 = 0;

    auto STEP = [&](const char* w1c, const char* w2r, char* w1f_, char* w2f_,
                    const unsigned char* g1, const unsigned char* g2,
                    bool doStage, bool doB,
                    long hin0, long hin1, long& hout0, long& hout1,
                    int b1off, bool last) {
        if (doStage) {
            GL16(g1 + t * 16, w1f_ + t * 16);
            GL16(g1 + 4096 + t * 16, w1f_ + 4096 + t * 16);
            GL16(g2 + t * 16, w2f_ + t * 16);
            GL16(g2 + 4096 + t * 16, w2f_ + 4096 + t * 16);
        }
        // A-part fragment loads (paired b128) + MFMAs
        long w1fr[2][8];
#pragma unroll
        for (int h = 0; h < 2; ++h)
#pragma unroll
            for (int kp = 0; kp < 4; ++kp) {
                long2v q = *(const long2v*)(w1c + (h * 4 + kp) * 1024 + lane * 16);
                w1fr[h][kp * 2] = q.x;
                w1fr[h][kp * 2 + 1] = q.y;
            }
        f32x4 ha[2][2];
#pragma unroll
        for (int tf = 0; tf < 2; ++tf)
#pragma unroll
            for (int h = 0; h < 2; ++h) ha[tf][h] = f32x4{0.f, 0.f, 0.f, 0.f};
#pragma unroll
        for (int ks = 0; ks < 8; ++ks) {
            ha[0][0] = mfma8(w1fr[0][ks], xr[0][ks], ha[0][0]);
            ha[0][1] = mfma8(w1fr[1][ks], xr[0][ks], ha[0][1]);
            ha[1][0] = mfma8(w1fr[0][ks], xr[1][ks], ha[1][0]);
            ha[1][1] = mfma8(w1fr[1][ks], xr[1][ks], ha[1][1]);
        }
        // B-part: previous step's H (in regs) @ W2(prev) -- independent of gelu
        if (doB) {
#pragma unroll
            for (int np = 0; np < 8; ++np) {
                long2v q = *(const long2v*)(w2r + np * 1024 + lane * 16);
                yacc[0][np * 2]     = mfma8(hin0, q.x, yacc[0][np * 2]);
                yacc[1][np * 2]     = mfma8(hin1, q.x, yacc[1][np * 2]);
                yacc[0][np * 2 + 1] = mfma8(hin0, q.y, yacc[0][np * 2 + 1]);
                yacc[1][np * 2 + 1] = mfma8(hin1, q.y, yacc[1][np * 2 + 1]);
            }
        }
        // gelu (sigmoid form) + pack + quad exchange -> hout
        float4 bv0 = *(const float4*)(b1lds + b1off + l4 * 16);
        float4 bv1 = *(const float4*)(b1lds + b1off + 64 + l4 * 16);
#pragma unroll
        for (int tf = 0; tf < 2; ++tf) {
            unsigned pp[2];
#pragma unroll
            for (int h = 0; h < 2; ++h) {
                const float* bb = h ? (const float*)&bv1 : (const float*)&bv0;
                float g[4];
#pragma unroll
                for (int j = 0; j < 4; ++j) {
                    float vv = ha[tf][h][j] + bb[j];
                    g[j] = vv * __builtin_amdgcn_rcpf(1.0f + __builtin_amdgcn_exp2f(-2.4554672f * vv));
                }
                pp[h] = pk8_hi(g[2], g[3], pk8_lo(g[0], g[1], 0u));
            }
            int src0 = l15 + ((l4 & 1) * 2) * 16;
            int a0 = __shfl((int)pp[0], src0);
            int a1 = __shfl((int)pp[1], src0);
            int b0 = __shfl((int)pp[0], src0 + 16);
            int b1x = __shfl((int)pp[1], src0 + 16);
            unsigned lo = (l4 < 2) ? (unsigned)a0 : (unsigned)a1;
            unsigned hi = (l4 < 2) ? (unsigned)b0 : (unsigned)b1x;
            long hv = (long)(((unsigned long)hi << 32) | (unsigned long)lo);
            if (tf == 0) hout0 = hv; else hout1 = hv;
        }
        __builtin_amdgcn_sched_barrier(0);
        if (last) asm volatile("s_waitcnt vmcnt(0)" ::: "memory");
        else      asm volatile("s_waitcnt vmcnt(6)" ::: "memory");
        __builtin_amdgcn_s_barrier();
        __builtin_amdgcn_sched_barrier(0);
    };

    const char *w1cur = W1S0, *w1nxt = W1S1, *w1fil = W1S2;
    const char *w2red = W2S3, *w2cur = W2S0, *w2nxt = W2S1, *w2fil = W2S2;
    const unsigned char* g1 = w1e + 16384;
    const unsigned char* g2 = w2e + 16384;
    int b1off = 0;

#define ROTATE() { const char* _a = w1cur; w1cur = w1nxt; w1nxt = w1fil; w1fil = _a; \
                   const char* _b = w2red; w2red = w2cur; w2cur = w2nxt; w2nxt = w2fil; w2fil = _b; \
                   g1 += 8192; g2 += 8192; b1off += 128; }

    // step 0: A only
    STEP(w1cur, w2red, (char*)w1fil, (char*)w2fil, g1, g2, true, false,
         hfB0, hfB1, hfA0, hfA1, b1off, false);
    ROTATE();

    for (int i = 0; i < 15; ++i) {
        // step s = 2i+1 (odd): consume hfA, produce hfB
        STEP(w1cur, w2red, (char*)w1fil, (char*)w2fil, g1, g2, true, true,
             hfA0, hfA1, hfB0, hfB1, b1off, false);
        ROTATE();
        // step s+1 = 2i+2 (even): consume hfB, produce hfA
        STEP(w1cur, w2red, (char*)w1fil, (char*)w2fil, g1, g2, (i < 14), true,
             hfB0, hfB1, hfA0, hfA1, b1off, (i == 14));
        ROTATE();
    }
    // step 31: consume hfA, produce hfB; no staging
    STEP(w1cur, w2red, (char*)W1S0, (char*)W2S0, g1, g2, false, true,
         hfA0, hfA1, hfB0, hfB1, b1off, true);
    // final B: hfrag(31) @ W2(31) (= w2cur, no rotation after step 31)
#pragma unroll
    for (int np = 0; np < 8; ++np) {
        long2v q = *(const long2v*)(w2cur + np * 1024 + lane * 16);
        yacc[0][np * 2]     = mfma8(hfB0, q.x, yacc[0][np * 2]);
        yacc[1][np * 2]     = mfma8(hfB1, q.x, yacc[1][np * 2]);
        yacc[0][np * 2 + 1] = mfma8(hfB0, q.y, yacc[0][np * 2 + 1]);
        yacc[1][np * 2 + 1] = mfma8(hfB1, q.y, yacc[1][np * 2 + 1]);
    }
#undef ROTATE

    // epilogue: direct bf16 stores (row = 512B, 32B segments per 16-lane group)
    char* Yg = (char*)(Y + ((size_t)e * BE + row0) * 256);
#pragma unroll
    for (int nc = 0; nc < 16; ++nc) {
        float b2v = b2[e * 256 + nc * 16 + l15];
#pragma unroll
        for (int tf = 0; tf < 2; ++tf)
#pragma unroll
            for (int j = 0; j < 4; ++j) {
                int row = w * 32 + tf * 16 + l4 * 4 + j;
                *(unsigned short*)(Yg + row * 512 + (nc * 16 + l15) * 2) =
                    f2bf(yacc[tf][nc][j] + b2v);
            }
    }
}

// Gather expert outputs (bf16), gate, add residual, write NCHW.
__global__ __launch_bounds__(256) void k_gather(const float* __restrict__ input,
                                                const unsigned short* __restrict__ Y,
                                                const int2* __restrict__ slots,
                                                const float2* __restrict__ gates,
                                                const float* __restrict__ ls,
                                                float* __restrict__ out) {
    __shared__ float acc[32][257];
    int t = threadIdx.x;
    int n = blockIdx.x >> 5, y = blockIdx.x & 31;

    {
        int tl = t & 31, chunk = t >> 5;
        int tok = n * 1024 + y * 32 + tl;
        int2  sl = slots[tok];
        float2 gw = gates[tok];
        int c0 = chunk * 32;
#pragma unroll
        for (int i = 0; i < 4; ++i) {
            int c = c0 + i * 8;
            float v[8];
#pragma unroll
            for (int k = 0; k < 8; ++k) v[k] = 0.f;
            if (sl.x >= 0) {
                bf16x8 yv = *(const bf16x8*)(Y + (size_t)sl.x * 256 + c);
#pragma unroll
                for (int k = 0; k < 8; ++k) v[k] += gw.x * bf2f((unsigned short)yv[k]);
            }
            if (sl.y >= 0) {
                bf16x8 yv = *(const bf16x8*)(Y + (size_t)sl.y * 256 + c);
#pragma unroll
                for (int k = 0; k < 8; ++k) v[k] += gw.y * bf2f((unsigned short)yv[k]);
            }
#pragma unroll
            for (int k = 0; k < 8; ++k) acc[tl][c + k] = v[k];
        }
    }
    __syncthreads();
    {
        int x = t & 31, c8 = t >> 5;
        size_t base = (size_t)n * 256 * 1024 + (size_t)y * 32 + x;
#pragma unroll
        for (int p = 0; p < 32; ++p) {
            int c = p * 8 + c8;
            size_t id = base + (size_t)c * 1024;
            out[id] = input[id] + ls[c] * acc[x][c];
        }
    }
}

extern "C" void kernel_launch(void* const* d_in, const int* in_sizes, int n_in,
                              void* d_out, int out_size, void* d_ws, size_t ws_size,
                              hipStream_t stream) {
    const float* input = (const float*)d_in[0];
    const float* dwk   = (const float*)d_in[1];
    const float* dwb   = (const float*)d_in[2];
    const float* gamma = (const float*)d_in[3];
    const float* beta  = (const float*)d_in[4];
    const float* rw    = (const float*)d_in[5];
    const float* w1    = (const float*)d_in[6];
    const float* b1    = (const float*)d_in[7];
    const float* w2    = (const float*)d_in[8];
    const float* b2    = (const float*)d_in[9];
    const float* ls    = (const float*)d_in[10];

    char* ws = (char*)d_ws;
    // xcb (64MiB bf16 NCHW conv out) aliases Yb (40MiB): xcb dead before k_mlp writes Yb.
    unsigned short* xcb  = (unsigned short*)ws;
    unsigned short* Yb   = (unsigned short*)ws;
    unsigned*       xf8  = (unsigned*)(ws + 83886080);         // 8MB fp8 x
    unsigned char*  w1p  = (unsigned char*)(ws + 100663296);   // 2MB paired tiles
    unsigned char*  w2p  = (unsigned char*)(ws + 104857600);   // 2MB paired tiles
    int*            rtok = (int*)(ws + 109051904);             // 320KB
    int2*           slots = (int2*)(ws + 109379584);           // 256KB
    float2*         gates = (float2*)(ws + 109641728);         // 256KB
    int*            e01  = (int*)(ws + 109903872);             // 128KB
    int*            cnt  = (int*)(ws + 110035968);             // 8*64 ints

    k_init<<<1, NE * CNT_STRIDE, 0, stream>>>(cnt);
    k_conv<<<8192, 256, 0, stream>>>(input, dwk, dwb, xcb);
    k_lnr<<<1024, 512, 0, stream>>>(xcb, gamma, beta, rw, xf8, e01, gates);
    k_assign<<<128, 256, 0, stream>>>(e01, cnt, rtok, slots);
    k_pack_w1<<<512, 256, 0, stream>>>(w1, w1p);
    k_pack_w2<<<512, 256, 0, stream>>>(w2, w2p);
    k_mlp<<<640, 256, 0, stream>>>((const unsigned char*)xf8, w1p, w2p, b1, b2, cnt, rtok, Yb);
    k_gather<<<1024, 256, 0, stream>>>(input, Yb, slots, gates, ls, (float*)d_out);
}

// Round 13
// 174.575 us; speedup vs baseline: 1.3660x; 1.1170x over previous
//
#include <hip/hip_runtime.h>
#include <math.h>

#define TOK 32768
#define CH  256
#define HIDN 1024
#define NE  8
#define BE  10240
#define CNT_STRIDE 64

typedef __attribute__((ext_vector_type(8))) short bf16x8;
typedef __attribute__((ext_vector_type(4))) float f32x4;
typedef __attribute__((ext_vector_type(2))) long long2v;

__device__ __forceinline__ unsigned short f2bf(float f) {
    unsigned u = __builtin_bit_cast(unsigned, f);
    unsigned r = 0x7FFFu + ((u >> 16) & 1u);
    return (unsigned short)((u + r) >> 16);
}
__device__ __forceinline__ float bf2f(unsigned short u) {
    return __builtin_bit_cast(float, (unsigned)u << 16);
}
__device__ __forceinline__ unsigned pk8_lo(float a, float b, unsigned old) {
    return (unsigned)__builtin_amdgcn_cvt_pk_fp8_f32(a, b, (int)old, false);
}
__device__ __forceinline__ unsigned pk8_hi(float a, float b, unsigned old) {
    return (unsigned)__builtin_amdgcn_cvt_pk_fp8_f32(a, b, (int)old, true);
}
__device__ __forceinline__ f32x4 mfma8(long a, long b, f32x4 c) {
    return __builtin_amdgcn_mfma_f32_16x16x32_fp8_fp8(a, b, c, 0, 0, 0);
}

typedef __attribute__((address_space(3))) void lds_t;
typedef const __attribute__((address_space(1))) void gm_t;
#define GL16(gp, lp) __builtin_amdgcn_global_load_lds((gm_t*)(gp), (lds_t*)(lp), 16, 0, 0)

__global__ void k_init(int* cnt) { cnt[threadIdx.x] = 0; }

// Depthwise 7x7 conv + bias. Block = one (n,c) image staged to LDS; each thread
// computes 4 consecutive-x outputs of one row -> one packed fp8 4B store.
__global__ __launch_bounds__(256) void k_conv(const float* __restrict__ in,
                                              const float* __restrict__ kern,
                                              const float* __restrict__ bias,
                                              unsigned char* __restrict__ xc8) {
    __shared__ float img[1024];
    __shared__ float kwl[49];
    int t = threadIdx.x;
    int bid = blockIdx.x;          // bid = n*256 + c
    int c = bid & 255;

    GL16(in + (size_t)bid * 1024 + t * 4, (char*)img + t * 16);
    if (t < 49) kwl[t] = kern[c * 49 + t];
    __syncthreads();

    int x0 = (t & 7) * 4, y = t >> 3;
    float b0 = bias[c];
    float acc[4] = {b0, b0, b0, b0};
#pragma unroll
    for (int jr = 0; jr < 7; ++jr) {
        int yy = y + jr - 3;
        if ((unsigned)yy < 32u) {
            float row[10];
#pragma unroll
            for (int k = 0; k < 10; ++k) {
                int xx = x0 - 3 + k;
                row[k] = ((unsigned)xx < 32u) ? img[yy * 32 + xx] : 0.f;
            }
#pragma unroll
            for (int kx = 0; kx < 7; ++kx) {
                float kv = kwl[jr * 7 + kx];
#pragma unroll
                for (int o = 0; o < 4; ++o) acc[o] = fmaf(row[o + kx], kv, acc[o]);
            }
        }
    }
    unsigned u = pk8_lo(acc[0], acc[1], 0u);
    u = pk8_hi(acc[2], acc[3], u);
    *(unsigned*)(xc8 + (size_t)bid * 1024 + y * 32 + x0) = u;
}

// LN + router: block = (n,y) row. Coalesced fp8 4B loads, decode, LDS
// transpose, then per-wave LN + top-2 router.
__global__ __launch_bounds__(512) void k_lnr(const unsigned char* __restrict__ xc8,
                                             const float* __restrict__ gamma,
                                             const float* __restrict__ beta,
                                             const float* __restrict__ rw,
                                             unsigned* __restrict__ xf8,
                                             int* __restrict__ e01,
                                             float2* __restrict__ gates) {
    __shared__ float acc[32][260];
    int t = threadIdx.x;
    int n = blockIdx.x >> 5, y = blockIdx.x & 31;
    int x4 = t & 7, ch = t >> 3;   // ch in [0,64)

#pragma unroll
    for (int i = 0; i < 4; ++i) {
        int c = i * 64 + ch;
        unsigned word = *(const unsigned*)(xc8 + ((size_t)(n * 256 + c)) * 1024 + y * 32 + x4 * 4);
        acc[x4 * 4 + 0][c] = __builtin_amdgcn_cvt_f32_fp8((int)word, 0);
        acc[x4 * 4 + 1][c] = __builtin_amdgcn_cvt_f32_fp8((int)word, 1);
        acc[x4 * 4 + 2][c] = __builtin_amdgcn_cvt_f32_fp8((int)word, 2);
        acc[x4 * 4 + 3][c] = __builtin_amdgcn_cvt_f32_fp8((int)word, 3);
    }
    __syncthreads();

    int lane = t & 63, w = t >> 6;
    float4 g4 = ((const float4*)gamma)[lane];
    float4 b4 = ((const float4*)beta)[lane];
    int c0 = lane * 4;
    float4 rwv[8];
#pragma unroll
    for (int j = 0; j < 4; ++j) {
        rwv[j * 2]     = *(const float4*)(rw + (size_t)(c0 + j) * 8);
        rwv[j * 2 + 1] = *(const float4*)(rw + (size_t)(c0 + j) * 8 + 4);
    }

#pragma unroll
    for (int k = 0; k < 4; ++k) {
        int tl = w * 4 + k;
        float4 v = *(const float4*)&acc[tl][lane * 4];
        float s = v.x + v.y + v.z + v.w;
        float q = v.x * v.x + v.y * v.y + v.z * v.z + v.w * v.w;
#pragma unroll
        for (int m = 1; m < 64; m <<= 1) { s += __shfl_xor(s, m); q += __shfl_xor(q, m); }
        float mean = s * (1.0f / 256.0f);
        float var  = q * (1.0f / 256.0f) - mean * mean;
        float rstd = rsqrtf(var + 1e-6f);

        float xn[4];
        xn[0] = (v.x - mean) * rstd * g4.x + b4.x;
        xn[1] = (v.y - mean) * rstd * g4.y + b4.y;
        xn[2] = (v.z - mean) * rstd * g4.z + b4.z;
        xn[3] = (v.w - mean) * rstd * g4.w + b4.w;

        unsigned px = pk8_lo(xn[0], xn[1], 0u);
        px = pk8_hi(xn[2], xn[3], px);
        int tok = n * 1024 + y * 32 + tl;
        xf8[tok * 64 + lane] = px;

        float p[8];
#pragma unroll
        for (int e = 0; e < 8; ++e) p[e] = 0.f;
#pragma unroll
        for (int j = 0; j < 4; ++j) {
            float xv = xn[j];
            const float* r0 = (const float*)&rwv[j * 2];
#pragma unroll
            for (int e = 0; e < 8; ++e) p[e] += xv * r0[e];
        }
#pragma unroll
        for (int m = 1; m < 64; m <<= 1) {
#pragma unroll
            for (int e = 0; e < 8; ++e) p[e] += __shfl_xor(p[e], m);
        }
        if (lane == 0) {
            int e0 = 0; float l0 = p[0];
#pragma unroll
            for (int e = 1; e < 8; ++e) if (p[e] > l0) { l0 = p[e]; e0 = e; }
            int e1 = -1; float l1 = -3.4e38f;
#pragma unroll
            for (int e = 0; e < 8; ++e) if (e != e0 && p[e] > l1) { l1 = p[e]; e1 = e; }
            float tt = expf(l1 - l0);
            float w0 = 1.0f / (1.0f + tt);
            e01[tok] = e0 | (e1 << 8);
            gates[tok] = make_float2(w0, 1.0f - w0);
        }
    }
}

// Hierarchical capacity assignment.
__global__ __launch_bounds__(256) void k_assign(const int* __restrict__ e01,
                                                int* __restrict__ cnt,
                                                int* __restrict__ row_token,
                                                int2* __restrict__ slots) {
    __shared__ int lcnt[8];
    __shared__ int base[8];
    int t = threadIdx.x;
    if (t < 8) lcnt[t] = 0;
    __syncthreads();
    int tok = blockIdx.x * 256 + t;
    int ee = e01[tok];
    int e0 = ee & 255, e1 = (ee >> 8) & 255;
    int lp0 = atomicAdd(&lcnt[e0], 1);
    int lp1 = atomicAdd(&lcnt[e1], 1);
    __syncthreads();
    if (t < 8) base[t] = atomicAdd(cnt + t * CNT_STRIDE, lcnt[t]);
    __syncthreads();
    int pos0 = base[e0] + lp0;
    int pos1 = base[e1] + lp1;
    int slot0 = (pos0 < BE) ? e0 * BE + pos0 : -1;
    int slot1 = (pos1 < BE) ? e1 * BE + pos1 : -1;
    if (slot0 >= 0) row_token[slot0] = tok;
    if (slot1 >= 0) row_token[slot1] = tok;
    slots[tok] = make_int2(slot0, slot1);
}

// Pack W1 [E][C=256][H=1024] f32 -> paired MFMA A-operand tiles, fp8.
__global__ __launch_bounds__(256) void k_pack_w1(const float* __restrict__ w1,
                                                 unsigned char* __restrict__ w1p) {
    int s = blockIdx.x * 256 + threadIdx.x;
    int l = s & 63, tile = s >> 6;
    int kp = tile & 3, h = (tile >> 2) & 1, hc = (tile >> 3) & 31, e = tile >> 8;
    int l15 = l & 15, l4 = l >> 4;
    int hid = hc * 32 + h * 16 + l15;
    int ch0 = kp * 64 + l4 * 8;
    const float* s0 = w1 + ((size_t)e * 256 + ch0) * 1024 + hid;
    float v[8], u[8];
#pragma unroll
    for (int b = 0; b < 8; ++b) { v[b] = s0[b * 1024]; u[b] = s0[(b + 32) * 1024]; }
    uint4 o;
    o.x = pk8_hi(v[2], v[3], pk8_lo(v[0], v[1], 0u));
    o.y = pk8_hi(v[6], v[7], pk8_lo(v[4], v[5], 0u));
    o.z = pk8_hi(u[2], u[3], pk8_lo(u[0], u[1], 0u));
    o.w = pk8_hi(u[6], u[7], pk8_lo(u[4], u[5], 0u));
    *(uint4*)(w1p + (size_t)tile * 1024 + l * 16) = o;
}

// Pack W2 [E][H=1024][C=256] f32 -> A-operand-style tiles with H's natural
// k-permutation baked in: k-position p holds hid 16*((p>>2)&1)+4*(p>>3)+(p&3),
// so gelu output (C-layout) feeds B-MFMA directly with ZERO shuffles.
__global__ __launch_bounds__(256) void k_pack_w2(const float* __restrict__ w2,
                                                 unsigned char* __restrict__ w2p) {
    int s = blockIdx.x * 256 + threadIdx.x;
    int l = s & 63, tile = s >> 6;
    int np = tile & 7, hc = (tile >> 3) & 31, e = tile >> 8;
    int l15 = l & 15, l4 = l >> 4;
    float v[8], u[8];
#pragma unroll
    for (int b = 0; b < 8; ++b) {
        int hidl = ((b >> 2) & 1) * 16 + l4 * 4 + (b & 3);
        const float* s0 = w2 + ((size_t)e * 1024 + hc * 32 + hidl) * 256 + np * 32 + l15;
        v[b] = s0[0];
        u[b] = s0[16];
    }
    uint4 o;
    o.x = pk8_hi(v[2], v[3], pk8_lo(v[0], v[1], 0u));
    o.y = pk8_hi(v[6], v[7], pk8_lo(v[4], v[5], 0u));
    o.z = pk8_hi(u[2], u[3], pk8_lo(u[0], u[1], 0u));
    o.w = pk8_hi(u[6], u[7], pk8_lo(u[4], u[5], 0u));
    *(uint4*)(w2p + (size_t)tile * 1024 + l * 16) = o;
}

// Fused expert MLP v6: 256 threads (4 waves), 64 rows/block, e = bid&7.
// 16 tokens/wave -> ~130 regs/wave -> 3 waves/SIMD. Zero-shuffle H->B via
// permuted W2 pack (B-MFMA: A=W2, B=H). W1 2-buf + W2 3-buf LDS (45KB,
// 3 blocks/CU), 1-ahead prefetch, counted vmcnt(2), 1 barrier/step.
__global__ __launch_bounds__(256, 3) void k_mlp(const unsigned char* __restrict__ xf8,
                                                const unsigned char* __restrict__ w1p,
                                                const unsigned char* __restrict__ w2p,
                                                const float* __restrict__ b1,
                                                const float* __restrict__ b2,
                                                const int* __restrict__ cnt,
                                                const int* __restrict__ row_token,
                                                unsigned short* __restrict__ Y) {
    int bid = blockIdx.x;
    int e = bid & 7;
    int row0 = (bid >> 3) * 64;
    int nrows = min(cnt[e * CNT_STRIDE], BE);
    if (row0 >= nrows) return;

    __shared__ char smem[45056];
    char* const W1S0 = smem;
    char* const W1S1 = smem + 8192;
    char* const W2S0 = smem + 16384;
    char* const W2S1 = smem + 24576;
    char* const W2S2 = smem + 32768;
    char* const b1lds = smem + 40960;

    int t = threadIdx.x;
    int w = t >> 6, lane = t & 63;
    int l15 = lane & 15, l4 = lane >> 4;

    const unsigned char* w1e = w1p + (size_t)e * 262144;
    const unsigned char* w2e = w2p + (size_t)e * 262144;

    // tokens + X -> VGPR (8 loads)
    int ri = row0 + w * 16 + l15;
    int tok0 = (ri < nrows) ? row_token[e * BE + ri] : 0;
    long xr[8];
#pragma unroll
    for (int ks = 0; ks < 8; ++ks)
        xr[ks] = *(const long*)(xf8 + (size_t)tok0 * 256 + ks * 32 + l4 * 8);

    // prologue: b1, W1(0), W2(0)
    GL16((const char*)(b1 + e * HIDN) + t * 16, b1lds + t * 16);
    GL16(w1e + t * 16, W1S0 + t * 16);
    GL16(w1e + 4096 + t * 16, W1S0 + 4096 + t * 16);
    GL16(w2e + t * 16, W2S0 + t * 16);
    GL16(w2e + 4096 + t * 16, W2S0 + 4096 + t * 16);
    __builtin_amdgcn_sched_barrier(0);
    asm volatile("s_waitcnt vmcnt(2)" ::: "memory");
    __builtin_amdgcn_s_barrier();
    __builtin_amdgcn_sched_barrier(0);

    f32x4 yacc[16];
#pragma unroll
    for (int nc = 0; nc < 16; ++nc) yacc[nc] = f32x4{0.f, 0.f, 0.f, 0.f};

    long hfA = 0, hfB = 0;

    auto STEP = [&](const char* w1c, const char* w2r, char* w1f_, char* w2f_,
                    const unsigned char* g1, const unsigned char* g2,
                    bool doStage, bool doB, long hin, long& hout,
                    int b1off, bool last) {
        if (doStage) {
            GL16(g1 + t * 16, w1f_ + t * 16);
            GL16(g1 + 4096 + t * 16, w1f_ + 4096 + t * 16);
            GL16(g2 + t * 16, w2f_ + t * 16);
            GL16(g2 + 4096 + t * 16, w2f_ + 4096 + t * 16);
        }
        // A: ha[h] = W1-tile(h) @ X   (D: col=token l15, row=hid l4*4+j)
        long w1fr[2][8];
#pragma unroll
        for (int h = 0; h < 2; ++h)
#pragma unroll
            for (int kp = 0; kp < 4; ++kp) {
                long2v q = *(const long2v*)(w1c + (h * 4 + kp) * 1024 + lane * 16);
                w1fr[h][kp * 2] = q.x;
                w1fr[h][kp * 2 + 1] = q.y;
            }
        f32x4 ha0 = f32x4{0.f, 0.f, 0.f, 0.f};
        f32x4 ha1 = f32x4{0.f, 0.f, 0.f, 0.f};
#pragma unroll
        for (int ks = 0; ks < 8; ++ks) {
            ha0 = mfma8(w1fr[0][ks], xr[ks], ha0);
            ha1 = mfma8(w1fr[1][ks], xr[ks], ha1);
        }
        // B: yacc += W2(prev) @ H(prev)  (A=W2, B=H; zero shuffles)
        if (doB) {
#pragma unroll
            for (int np = 0; np < 8; ++np) {
                long2v q = *(const long2v*)(w2r + np * 1024 + lane * 16);
                yacc[np * 2]     = mfma8(q.x, hin, yacc[np * 2]);
                yacc[np * 2 + 1] = mfma8(q.y, hin, yacc[np * 2 + 1]);
            }
        }
        // gelu (sigmoid form) + pack -> hout (natural order = B-operand)
        float4 bv0 = *(const float4*)(b1lds + b1off + l4 * 16);
        float4 bv1 = *(const float4*)(b1lds + b1off + 64 + l4 * 16);
        float g[4];
#pragma unroll
        for (int j = 0; j < 4; ++j) {
            float vv = ha0[j] + ((const float*)&bv0)[j];
            g[j] = vv * __builtin_amdgcn_rcpf(1.0f + __builtin_amdgcn_exp2f(-2.4554672f * vv));
        }
        unsigned p0 = pk8_hi(g[2], g[3], pk8_lo(g[0], g[1], 0u));
#pragma unroll
        for (int j = 0; j < 4; ++j) {
            float vv = ha1[j] + ((const float*)&bv1)[j];
            g[j] = vv * __builtin_amdgcn_rcpf(1.0f + __builtin_amdgcn_exp2f(-2.4554672f * vv));
        }
        unsigned p1 = pk8_hi(g[2], g[3], pk8_lo(g[0], g[1], 0u));
        hout = (long)(((unsigned long)p1 << 32) | (unsigned long)p0);

        __builtin_amdgcn_sched_barrier(0);
        if (last) asm volatile("s_waitcnt vmcnt(0)" ::: "memory");
        else      asm volatile("s_waitcnt vmcnt(2)" ::: "memory");
        __builtin_amdgcn_s_barrier();
        __builtin_amdgcn_sched_barrier(0);
    };

    const char *w1r = W1S0, *w1f = W1S1;
    const char *w2red = W2S2, *w2cur = W2S0, *w2fil = W2S1;
    const unsigned char* g1 = w1e + 8192;
    const unsigned char* g2 = w2e + 8192;
    int b1off = 0;

#define ROTATE() { const char* _a = w1r; w1r = w1f; w1f = _a; \
                   const char* _b = w2red; w2red = w2cur; w2cur = w2fil; w2fil = _b; \
                   g1 += 8192; g2 += 8192; b1off += 128; }

    // step 0: A only, produce h(0)->hfA
    STEP(w1r, w2red, (char*)w1f, (char*)w2fil, g1, g2, true, false, hfB, hfA, b1off, false);
    ROTATE();
    for (int i = 0; i < 5; ++i) {
        STEP(w1r, w2red, (char*)w1f, (char*)w2fil, g1, g2, true, true, hfA, hfB, b1off, false); ROTATE();
        STEP(w1r, w2red, (char*)w1f, (char*)w2fil, g1, g2, true, true, hfB, hfA, b1off, false); ROTATE();
        STEP(w1r, w2red, (char*)w1f, (char*)w2fil, g1, g2, true, true, hfA, hfB, b1off, false); ROTATE();
        STEP(w1r, w2red, (char*)w1f, (char*)w2fil, g1, g2, true, true, hfB, hfA, b1off, false); ROTATE();
        STEP(w1r, w2red, (char*)w1f, (char*)w2fil, g1, g2, true, true, hfA, hfB, b1off, false); ROTATE();
        STEP(w1r, w2red, (char*)w1f, (char*)w2fil, g1, g2, true, true, hfB, hfA, b1off, false); ROTATE();
    }
    // step 31: no stage, consume h(30)=hfA, produce h(31)=hfB
    STEP(w1r, w2red, (char*)w1f, (char*)w2fil, g1, g2, false, true, hfA, hfB, b1off, true);
    // final B: h(31) @ W2(31) (= w2cur)
#pragma unroll
    for (int np = 0; np < 8; ++np) {
        long2v q = *(const long2v*)(w2cur + np * 1024 + lane * 16);
        yacc[np * 2]     = mfma8(q.x, hfB, yacc[np * 2]);
        yacc[np * 2 + 1] = mfma8(q.y, hfB, yacc[np * 2 + 1]);
    }
#undef ROTATE

    // epilogue: +b2; LDS transpose (520B pitch) -> coalesced bf16 rows.
    // yacc layout: col l15 = token (w*16+l15), row l4*4+jj = outch_sub of nc.
#pragma unroll
    for (int nc = 0; nc < 16; ++nc) {
        float4 bv = *(const float4*)(b2 + e * 256 + nc * 16 + l4 * 4);
#pragma unroll
        for (int jj = 0; jj < 4; ++jj) yacc[nc][jj] += ((const float*)&bv)[jj];
    }
    __syncthreads();
    int lrow = w * 16 + l15;
#pragma unroll
    for (int nc = 0; nc < 16; ++nc) {
#pragma unroll
        for (int jp = 0; jp < 2; ++jp) {
            unsigned pk = (unsigned)f2bf(yacc[nc][jp * 2]) |
                          ((unsigned)f2bf(yacc[nc][jp * 2 + 1]) << 16);
            *(unsigned*)(smem + lrow * 520 + (nc * 16 + l4 * 4 + jp * 2) * 2) = pk;
        }
    }
    __syncthreads();
    {
        char* Yg = (char*)(Y + ((size_t)e * BE + row0) * 256);
#pragma unroll
        for (int i = 0; i < 8; ++i) {
            int flat = i * 4096 + t * 16;
            int row = flat >> 9, off = flat & 511;
            *(int4*)(Yg + row * 512 + off) = *(const int4*)(smem + row * 520 + off);
        }
    }
}

// Gather expert outputs (bf16), gate, add residual, write NCHW.
__global__ __launch_bounds__(256) void k_gather(const float* __restrict__ input,
                                                const unsigned short* __restrict__ Y,
                                                const int2* __restrict__ slots,
                                                const float2* __restrict__ gates,
                                                const float* __restrict__ ls,
                                                float* __restrict__ out) {
    __shared__ float acc[32][257];
    int t = threadIdx.x;
    int n = blockIdx.x >> 5, y = blockIdx.x & 31;

    {
        int tl = t & 31, chunk = t >> 5;
        int tok = n * 1024 + y * 32 + tl;
        int2  sl = slots[tok];
        float2 gw = gates[tok];
        int c0 = chunk * 32;
#pragma unroll
        for (int i = 0; i < 4; ++i) {
            int c = c0 + i * 8;
            float v[8];
#pragma unroll
            for (int k = 0; k < 8; ++k) v[k] = 0.f;
            if (sl.x >= 0) {
                bf16x8 yv = *(const bf16x8*)(Y + (size_t)sl.x * 256 + c);
#pragma unroll
                for (int k = 0; k < 8; ++k) v[k] += gw.x * bf2f((unsigned short)yv[k]);
            }
            if (sl.y >= 0) {
                bf16x8 yv = *(const bf16x8*)(Y + (size_t)sl.y * 256 + c);
#pragma unroll
                for (int k = 0; k < 8; ++k) v[k] += gw.y * bf2f((unsigned short)yv[k]);
            }
#pragma unroll
            for (int k = 0; k < 8; ++k) acc[tl][c + k] = v[k];
        }
    }
    __syncthreads();
    {
        int x = t & 31, c8 = t >> 5;
        size_t base = (size_t)n * 256 * 1024 + (size_t)y * 32 + x;
#pragma unroll
        for (int p = 0; p < 32; ++p) {
            int c = p * 8 + c8;
            size_t id = base + (size_t)c * 1024;
            out[id] = input[id] + ls[c] * acc[x][c];
        }
    }
}

extern "C" void kernel_launch(void* const* d_in, const int* in_sizes, int n_in,
                              void* d_out, int out_size, void* d_ws, size_t ws_size,
                              hipStream_t stream) {
    const float* input = (const float*)d_in[0];
    const float* dwk   = (const float*)d_in[1];
    const float* dwb   = (const float*)d_in[2];
    const float* gamma = (const float*)d_in[3];
    const float* beta  = (const float*)d_in[4];
    const float* rw    = (const float*)d_in[5];
    const float* w1    = (const float*)d_in[6];
    const float* b1    = (const float*)d_in[7];
    const float* w2    = (const float*)d_in[8];
    const float* b2    = (const float*)d_in[9];
    const float* ls    = (const float*)d_in[10];

    char* ws = (char*)d_ws;
    // xc8 (16.8MB fp8 conv out) aliases Yb (40MB): xc8 dead before k_mlp writes Yb.
    unsigned char*  xc8  = (unsigned char*)ws;
    unsigned short* Yb   = (unsigned short*)ws;
    unsigned*       xf8  = (unsigned*)(ws + 83886080);         // 8MB fp8 x
    unsigned char*  w1p  = (unsigned char*)(ws + 100663296);   // 2MB paired tiles
    unsigned char*  w2p  = (unsigned char*)(ws + 104857600);   // 2MB permuted tiles
    int*            rtok = (int*)(ws + 109051904);             // 320KB
    int2*           slots = (int2*)(ws + 109379584);           // 256KB
    float2*         gates = (float2*)(ws + 109641728);         // 256KB
    int*            e01  = (int*)(ws + 109903872);             // 128KB
    int*            cnt  = (int*)(ws + 110035968);             // 8*64 ints

    k_init<<<1, NE * CNT_STRIDE, 0, stream>>>(cnt);
    k_conv<<<8192, 256, 0, stream>>>(input, dwk, dwb, xc8);
    k_lnr<<<1024, 512, 0, stream>>>(xc8, gamma, beta, rw, xf8, e01, gates);
    k_assign<<<128, 256, 0, stream>>>(e01, cnt, rtok, slots);
    k_pack_w1<<<512, 256, 0, stream>>>(w1, w1p);
    k_pack_w2<<<512, 256, 0, stream>>>(w2, w2p);
    k_mlp<<<1280, 256, 0, stream>>>((const unsigned char*)xf8, w1p, w2p, b1, b2, cnt, rtok, Yb);
    k_gather<<<1024, 256, 0, stream>>>(input, Yb, slots, gates, ls, (float*)d_out);
}